// Round 8
// baseline (13.633 us; speedup 1.0000x reference)
//
#include <hip/hip_runtime.h>

#define DEV __device__ __forceinline__
DEV float ex2(float x)  { return __builtin_amdgcn_exp2f(x); }
DEV float rcpa(float x) { return __builtin_amdgcn_rcpf(x); }

constexpr float LOG2E      = 1.4426950408889634f;
constexpr float CBRT_LOG2E = 1.1299472940779f;   // cbrt(log2 e); cube == LOG2E

typedef _Float16 h2_t  __attribute__((ext_vector_type(2)));
typedef _Float16 f16x8 __attribute__((ext_vector_type(8)));
typedef float    f32x4 __attribute__((ext_vector_type(4)));
union F8 { f16x8 v; h2_t h[4]; };

DEV h2_t pkrtz(float a, float b) {
    return __builtin_bit_cast(h2_t, __builtin_amdgcn_cvt_pkrtz(a, b));
}

// ============ fused single-launch kernel (B%16==0, I=256, O=128, G=8) =======
// Grid: 1-D (B/16)*8 blocks; block = 1024 thr = 16 waves (4/SIMD).
// XCD swizzle: o_tile = bid&7 (8 o-tiles == 8 XCDs, dispatch round-robins
// bid%8 -> XCD), so every block on an XCD shares the same W-strip/sc rows
// in that XCD's private L2 (kills the 32x W re-fetch from L3 after the
// harness's per-replay 256MB memset evicts L2).
// W loads are issued speculatively into registers before the verdict barrier
// so their latency hides under the trans-heavy basis evals.
__global__ __launch_bounds__(1024)
void kan_fused1k(const float* __restrict__ x, const float* __restrict__ w,
                 const float* __restrict__ sc, const float* __restrict__ bias,
                 const float* __restrict__ gp, float* __restrict__ out,
                 int B, int O)
{
    constexpr int I = 256;
    const int tid = threadIdx.x;
    const int bid = blockIdx.x;
    const int b0  = (bid >> 3) * 16;
    const int o0  = (bid & 7) * 16;

    __shared__ int   sbad;
    __shared__ f32x4 red[16][64];                // 16 KB cross-wave reduce

    if (tid == 0) sbad = 0;

    const int l   = tid & 63;
    const int kw  = tid >> 6;                    // wave id: k-chunk of 16 i
    const int row = l & 15;                      // A-row (b) / B-row (o)
    const int kq  = l >> 4;                      // k-quarter within fragment

    // ---- speculative sc==1 check: 16 rows x 256 = 1024 float4, 1/thread ----
    bool bad;
    {
        const float4 v = ((const float4*)(sc + (size_t)o0 * I))[tid];
        bad = (v.x != 1.f) | (v.y != 1.f) | (v.z != 1.f) | (v.w != 1.f);
    }

    // ---- speculative W prefetch into registers (overlaps eval phase) ----
    const float4* wp =
        (const float4*)(w + (size_t)(o0 + row) * 2048 + kw * 128 + kq * 8);
    float4 wreg[8];
#pragma unroll
    for (int e = 0; e < 4; ++e) {
        wreg[2*e]   = wp[e * 8];
        wreg[2*e+1] = wp[e * 8 + 1];
    }

    float gs[8];
#pragma unroll
    for (int g = 0; g < 8; ++g) gs[g] = gp[g] * CBRT_LOG2E;

    // ---- speculative basis evals -> a-fragments (i = kw*16 + e*4 + kq) ----
    f16x8 af[4];
#pragma unroll
    for (int e = 0; e < 4; ++e) {
        const int i = kw * 16 + e * 4 + kq;
        const float xv = x[(size_t)(b0 + row) * I + i];
        const float r  = rcpa(1.f + ex2(xv * (2.f * LOG2E)));
        const float ts = fmaf(-2.f * CBRT_LOG2E, r, CBRT_LOG2E); // tanh * C
        float bb[8]; float den = 1e-8f;
#pragma unroll
        for (int g = 0; g < 8; ++g) {
            const float df = ts - gs[g];
            const float d3 = df * df * fabsf(df);
            bb[g] = ex2(-d3);                    // == exp(-|d|^3)
            den += bb[g];
        }
        const float rd = rcpa(den);
        F8 u;
        u.h[0] = pkrtz(bb[0] * rd, bb[1] * rd);
        u.h[1] = pkrtz(bb[2] * rd, bb[3] * rd);
        u.h[2] = pkrtz(bb[4] * rd, bb[5] * rd);
        u.h[3] = pkrtz(bb[6] * rd, bb[7] * rd);
        af[e] = u.v;
    }

    __syncthreads();                             // sbad=0 visible; evals done
    if (bad) sbad = 1;
    __syncthreads();

    if (!sbad) {
        // ---- MFMA over this wave's 128-k chunk (W already in registers) ----
        f32x4 acc = {0.f, 0.f, 0.f, 0.f};
#pragma unroll
        for (int e = 0; e < 4; ++e) {
            const float4 u0 = wreg[2*e];
            const float4 u1 = wreg[2*e+1];
            F8 bf;
            bf.h[0] = pkrtz(u0.x, u0.y);
            bf.h[1] = pkrtz(u0.z, u0.w);
            bf.h[2] = pkrtz(u1.x, u1.y);
            bf.h[3] = pkrtz(u1.z, u1.w);
            acc = __builtin_amdgcn_mfma_f32_16x16x32_f16(af[e], bf.v, acc, 0, 0, 0);
        }

        // ---- 16-way cross-wave k-reduce + epilogue ----
        red[kw][l] = acc;
        __syncthreads();
        if (tid < 256) {
            const int ll = tid & 63;
            const int rr = tid >> 6;             // C/D reg index
            float s = 0.f;
#pragma unroll
            for (int wv = 0; wv < 16; ++wv)
                s += ((const float*)&red[wv][ll])[rr];
            // C/D map (m89): col = lane&15 -> o, row = (lane>>4)*4 + reg -> b
            const int oo  = o0 + (ll & 15);
            const int bb2 = b0 + (ll >> 4) * 4 + rr;
            out[(size_t)bb2 * O + oo] = s + bias[oo];
        }
    } else {
        // ---- slow path: direct compute (general sc), 1 thread/output ----
        if (tid < 256) {
            const int bt = b0 + (tid >> 4);
            const int ot = o0 + (tid & 15);
            float acc = 0.f;
            for (int i = 0; i < I; ++i) {
                const float xv = x[(size_t)bt * I + i];
                const float sv = sc[(size_t)ot * I + i];
                const float t  = xv / sv;
                const float e  = ex2(-2.f * LOG2E * fabsf(t));
                const float th = (1.f - e) / (1.f + e);
                const float xn = __builtin_copysignf(th, t);
                const float4* wv = (const float4*)(w + ((size_t)ot * I + i) * 8);
                const float4 w0 = wv[0];
                const float4 w1 = wv[1];
                const float wb[8] = {w0.x, w0.y, w0.z, w0.w,
                                     w1.x, w1.y, w1.z, w1.w};
                float den = 1e-8f, num = 0.f;
#pragma unroll
                for (int g = 0; g < 8; ++g) {
                    const float d  = fabsf(xn - gp[g]);
                    const float d3 = d * d * d;
                    const float bv = ex2(-d3 * LOG2E);
                    den += bv;
                    num += bv * wb[g];
                }
                acc += num / den;
            }
            out[(size_t)bt * O + ot] = acc + bias[ot];
        }
    }
}

// =================== generic fallback (any G/I/B/O) =========================
__global__ void kan_generic(const float* __restrict__ x, const float* __restrict__ w,
                            const float* __restrict__ sc, const float* __restrict__ bias,
                            const float* __restrict__ gp, float* __restrict__ out,
                            int B, int I, int O, int G)
{
    const int o    = blockIdx.x;
    const int wid  = threadIdx.x >> 6;
    const int lane = threadIdx.x & 63;
    const int b    = blockIdx.y * 4 + wid;
    if (b >= B) return;

    float acc = 0.f;
    for (int i = lane; i < I; i += 64) {
        const float xv = x[(size_t)b * I + i];
        const float sv = sc[(size_t)o * I + i];
        const float t  = xv / sv;
        const float at = fabsf(t);
        const float e  = ex2(-2.f * LOG2E * at);
        const float th = (1.f - e) / (1.f + e);
        const float xn = __builtin_copysignf(th, t);
        float den = 1e-8f, num = 0.f;
        for (int g = 0; g < G; ++g) {
            const float d  = fabsf(xn - gp[g]);
            const float d3 = d * d * d;
            const float bb = ex2(-d3 * LOG2E);
            den += bb;
            num += bb * w[((size_t)o * I + i) * G + g];
        }
        acc += num / den;
    }
#pragma unroll
    for (int off = 32; off; off >>= 1) acc += __shfl_xor(acc, off, 64);
    if (lane == 0) out[(size_t)b * O + o] = acc + bias[o];
}

extern "C" void kernel_launch(void* const* d_in, const int* in_sizes, int n_in,
                              void* d_out, int out_size, void* d_ws, size_t ws_size,
                              hipStream_t stream) {
    const float* x    = (const float*)d_in[0];
    const float* w    = (const float*)d_in[1];
    const float* sc   = (const float*)d_in[2];
    const float* bias = (const float*)d_in[3];
    const float* gp   = (const float*)d_in[4];
    float* out = (float*)d_out;

    const int O = in_sizes[3];
    const int G = in_sizes[4];
    const int I = in_sizes[2] / O;
    const int B = in_sizes[0] / I;

    if (I == 256 && G == 8 && O == 128 && (B & 15) == 0) {
        kan_fused1k<<<(B / 16) * 8, 1024, 0, stream>>>(x, w, sc, bias, gp, out, B, O);
    } else {
        dim3 grid(O, (B + 3) / 4);
        kan_generic<<<grid, 256, 0, stream>>>(x, w, sc, bias, gp, out, B, I, O, G);
    }
}

// Round 9
// 11.969 us; speedup vs baseline: 1.1391x; 1.1391x over previous
//
#include <hip/hip_runtime.h>

#define DEV __device__ __forceinline__
DEV float ex2(float x)  { return __builtin_amdgcn_exp2f(x); }
DEV float rcpa(float x) { return __builtin_amdgcn_rcpf(x); }

constexpr float LOG2E      = 1.4426950408889634f;
constexpr float CBRT_LOG2E = 1.1299472940779f;   // cbrt(log2 e); cube == LOG2E

typedef _Float16 h2_t  __attribute__((ext_vector_type(2)));
typedef _Float16 f16x8 __attribute__((ext_vector_type(8)));
typedef float    f32x4 __attribute__((ext_vector_type(4)));
union F8 { f16x8 v; h2_t h[4]; };

DEV h2_t pkrtz(float a, float b) {
    return __builtin_bit_cast(h2_t, __builtin_amdgcn_cvt_pkrtz(a, b));
}

// =========== fused single-launch kernel (I=256, G=8, 16x16 tiles) ===========
// Grid: (B/16, O/16); block = 1024 thr = 16 waves (4/SIMD, VGPR-bound max).
// Entire fast path runs speculatively; ONE barrier total (reduce + verdict).
// Reduce buffer is [reg][wave][lane] so all LDS ops are stride-4B (2-way,
// free) instead of the old stride-16B scalar reads (8-way conflict).
__global__ __launch_bounds__(1024)
void kan_fused1k(const float* __restrict__ x, const float* __restrict__ w,
                 const float* __restrict__ sc, const float* __restrict__ bias,
                 const float* __restrict__ gp, float* __restrict__ out,
                 int B, int O)
{
    constexpr int I = 256;
    const int tid = threadIdx.x;
    const int b0  = blockIdx.x * 16;
    const int o0  = blockIdx.y * 16;

    __shared__ float red[4][16][64];             // 16 KB, conflict-free layout
    __shared__ int   wbad[16];

    const int l   = tid & 63;
    const int kw  = tid >> 6;                    // wave id: k-chunk of 16 i
    const int row = l & 15;                      // A-row (b) / B-row (o)
    const int kq  = l >> 4;                      // k-quarter within fragment

    // ---- speculative sc==1 check: 1024 float4, 1/thread, coalesced ----
    bool bad;
    {
        const float4 v = ((const float4*)(sc + (size_t)o0 * I))[tid];
        bad = (v.x != 1.f) | (v.y != 1.f) | (v.z != 1.f) | (v.w != 1.f);
    }

    // ---- hoist x loads ahead of the trans chains ----
    float xr[4];
#pragma unroll
    for (int e = 0; e < 4; ++e)
        xr[e] = x[(size_t)(b0 + row) * I + kw * 16 + e * 4 + kq];

    float gs[8];
#pragma unroll
    for (int g = 0; g < 8; ++g) gs[g] = gp[g] * CBRT_LOG2E;

    // ---- basis evals -> a-fragments (i = kw*16 + e*4 + kq) ----
    f16x8 af[4];
#pragma unroll
    for (int e = 0; e < 4; ++e) {
        const float r  = rcpa(1.f + ex2(xr[e] * (2.f * LOG2E)));
        const float ts = fmaf(-2.f * CBRT_LOG2E, r, CBRT_LOG2E); // tanh * C
        float bb[8];
#pragma unroll
        for (int g = 0; g < 8; ++g) {
            const float df = ts - gs[g];
            const float d3 = df * df * fabsf(df);
            bb[g] = ex2(-d3);                    // == exp(-|d|^3)
        }
        const float s01 = bb[0] + bb[1], s23 = bb[2] + bb[3];
        const float s45 = bb[4] + bb[5], s67 = bb[6] + bb[7];
        const float den = (s01 + s23) + (s45 + s67) + 1e-8f;
        const float rd  = rcpa(den);
        F8 u;
        u.h[0] = pkrtz(bb[0] * rd, bb[1] * rd);
        u.h[1] = pkrtz(bb[2] * rd, bb[3] * rd);
        u.h[2] = pkrtz(bb[4] * rd, bb[5] * rd);
        u.h[3] = pkrtz(bb[6] * rd, bb[7] * rd);
        af[e] = u.v;
    }

    // ---- speculative MFMA over this wave's 128-k chunk, W streamed ----
    const float4* wp =
        (const float4*)(w + (size_t)(o0 + row) * 2048 + kw * 128 + kq * 8);
    f32x4 acc = {0.f, 0.f, 0.f, 0.f};
#pragma unroll
    for (int e = 0; e < 4; ++e) {
        const float4 u0 = wp[e * 8];
        const float4 u1 = wp[e * 8 + 1];
        F8 bf;
        bf.h[0] = pkrtz(u0.x, u0.y);
        bf.h[1] = pkrtz(u0.z, u0.w);
        bf.h[2] = pkrtz(u1.x, u1.y);
        bf.h[3] = pkrtz(u1.z, u1.w);
        acc = __builtin_amdgcn_mfma_f32_16x16x32_f16(af[e], bf.v, acc, 0, 0, 0);
    }

    // ---- publish partials + wave verdict; ONE barrier ----
    red[0][kw][l] = acc[0];
    red[1][kw][l] = acc[1];
    red[2][kw][l] = acc[2];
    red[3][kw][l] = acc[3];
    const int wany = __any((int)bad);
    if (l == 0) wbad[kw] = wany;
    __syncthreads();

    if (tid < 256) {
        int anybad = 0;
#pragma unroll
        for (int v2 = 0; v2 < 16; ++v2) anybad |= wbad[v2];
        const int ll = tid & 63;
        const int rr = tid >> 6;                 // C/D reg index
        if (!anybad) {
            float s = 0.f;
#pragma unroll
            for (int wv = 0; wv < 16; ++wv) s += red[rr][wv][ll];
            // C/D map (m89): col = lane&15 -> o, row = (lane>>4)*4 + reg -> b
            const int oo  = o0 + (ll & 15);
            const int bb2 = b0 + (ll >> 4) * 4 + rr;
            out[(size_t)bb2 * O + oo] = s + bias[oo];
        } else {
            // ---- slow path: direct compute (general sc), 1 thr/output ----
            const int bt = b0 + (tid >> 4);
            const int ot = o0 + (tid & 15);
            float acc2 = 0.f;
            for (int i = 0; i < I; ++i) {
                const float xv = x[(size_t)bt * I + i];
                const float sv = sc[(size_t)ot * I + i];
                const float t  = xv / sv;
                const float e  = ex2(-2.f * LOG2E * fabsf(t));
                const float th = (1.f - e) / (1.f + e);
                const float xn = __builtin_copysignf(th, t);
                const float4* wv4 = (const float4*)(w + ((size_t)ot * I + i) * 8);
                const float4 w0 = wv4[0];
                const float4 w1 = wv4[1];
                const float wb[8] = {w0.x, w0.y, w0.z, w0.w,
                                     w1.x, w1.y, w1.z, w1.w};
                float den = 1e-8f, num = 0.f;
#pragma unroll
                for (int g = 0; g < 8; ++g) {
                    const float d  = fabsf(xn - gp[g]);
                    const float d3 = d * d * d;
                    const float bv = ex2(-d3 * LOG2E);
                    den += bv;
                    num += bv * wb[g];
                }
                acc2 += num / den;
            }
            out[(size_t)bt * O + ot] = acc2 + bias[ot];
        }
    }
}

// =================== generic fallback (any G/I/B/O) =========================
__global__ void kan_generic(const float* __restrict__ x, const float* __restrict__ w,
                            const float* __restrict__ sc, const float* __restrict__ bias,
                            const float* __restrict__ gp, float* __restrict__ out,
                            int B, int I, int O, int G)
{
    const int o    = blockIdx.x;
    const int wid  = threadIdx.x >> 6;
    const int lane = threadIdx.x & 63;
    const int b    = blockIdx.y * 4 + wid;
    if (b >= B) return;

    float acc = 0.f;
    for (int i = lane; i < I; i += 64) {
        const float xv = x[(size_t)b * I + i];
        const float sv = sc[(size_t)o * I + i];
        const float t  = xv / sv;
        const float at = fabsf(t);
        const float e  = ex2(-2.f * LOG2E * at);
        const float th = (1.f - e) / (1.f + e);
        const float xn = __builtin_copysignf(th, t);
        float den = 1e-8f, num = 0.f;
        for (int g = 0; g < G; ++g) {
            const float d  = fabsf(xn - gp[g]);
            const float d3 = d * d * d;
            const float bb = ex2(-d3 * LOG2E);
            den += bb;
            num += bb * w[((size_t)o * I + i) * G + g];
        }
        acc += num / den;
    }
#pragma unroll
    for (int off = 32; off; off >>= 1) acc += __shfl_xor(acc, off, 64);
    if (lane == 0) out[(size_t)b * O + o] = acc + bias[o];
}

extern "C" void kernel_launch(void* const* d_in, const int* in_sizes, int n_in,
                              void* d_out, int out_size, void* d_ws, size_t ws_size,
                              hipStream_t stream) {
    const float* x    = (const float*)d_in[0];
    const float* w    = (const float*)d_in[1];
    const float* sc   = (const float*)d_in[2];
    const float* bias = (const float*)d_in[3];
    const float* gp   = (const float*)d_in[4];
    float* out = (float*)d_out;

    const int O = in_sizes[3];
    const int G = in_sizes[4];
    const int I = in_sizes[2] / O;
    const int B = in_sizes[0] / I;

    if (I == 256 && G == 8 && (B & 15) == 0 && (O & 15) == 0) {
        dim3 grid(B / 16, O / 16);
        kan_fused1k<<<grid, 1024, 0, stream>>>(x, w, sc, bias, gp, out, B, O);
    } else {
        dim3 grid(O, (B + 3) / 4);
        kan_generic<<<grid, 256, 0, stream>>>(x, w, sc, bias, gp, out, B, I, O, G);
    }
}